// Round 5
// baseline (6668.941 us; speedup 1.0000x reference)
//
#include <hip/hip_runtime.h>
#include <hip/hip_bf16.h>
#include <math.h>

// ConvLSTMClassifier on MI355X — 8-steps-per-launch, c-in-registers MFMA.
// gates[b,w,n] = bias[n] + sum_kx x[b,t,w+kx-1]*pxw[kx,n]
//              + sum_kx sum_ic h[b,w+kx-1,ic]*Bp[kx,n,ic],  n = g*128+ch.
// Fixed-origin indexing for the whole launch: slab row j <-> w = w0-9+j,
// output row m <-> w = w0-8+m (m = mf*16+krow*4+r). c[w] never leaves its
// lane's register across the 8 fused steps. Validity window [s+1, 142-s];
// invalid rows write h=0 so slabs stay clean.
// Block: 512 thr / 8 waves, owns M=128 w-rows x ALL 512 N. grid=(4,64)=256.

constexpr int kB  = 64;
constexpr int kCH = 128;
constexpr int kH  = 128;
constexpr int kW  = 512;
constexpr int kNC = 10;
constexpr int kT  = 8;     // fused steps per launch
constexpr int ROWS = 146;  // slab rows

typedef __attribute__((ext_vector_type(8))) short short8v;
typedef __attribute__((ext_vector_type(4))) float float4v;

__device__ __forceinline__ float fsig(float v) {
    return 1.0f / (1.0f + __expf(-v));
}
__device__ __forceinline__ float ftanh(float v) {
    float e = __expf(2.0f * v);
    return 1.0f - 2.0f / (e + 1.0f);
}

// ---------------------------------------------------------------------------
// Weight pack: Bp[kx][oc][ic] bf16, pxw[kx][oc] f32, pb[oc] f32.
// Also zeroes the pooled accumulator (ws is poisoned before timing).
// ---------------------------------------------------------------------------
__global__ __launch_bounds__(256) void pack_weights(
    const float* __restrict__ conv_w,  // [512][129][3][3]
    const float* __restrict__ conv_b,  // [512]
    short* __restrict__ Bp,            // [3][512][128]
    float* __restrict__ pxw,           // [3][512]
    float* __restrict__ pb,            // [512]
    float* __restrict__ pooled)        // [64][128]
{
    int idx = blockIdx.x * 256 + threadIdx.x;
    if (idx < 3 * 512 * 128) {
        int ic = idx & 127;
        int oc = (idx >> 7) & 511;
        int kx = idx >> 16;
        float v = conv_w[((oc * 129 + 1 + ic) * 3 + 1) * 3 + kx];
        __hip_bfloat16 hv = __float2bfloat16(v);
        Bp[idx] = *reinterpret_cast<short*>(&hv);
    }
    if (idx < 3 * 512) {
        int oc = idx & 511, kx = idx >> 9;
        pxw[idx] = conv_w[((oc * 129 + 0) * 3 + 1) * 3 + kx];
    }
    if (idx < 512) pb[idx] = conv_b[idx];
    if (idx < kB * kCH) pooled[idx] = 0.0f;
}

// ---------------------------------------------------------------------------
template <bool FIRST, bool LAST>
__global__ __launch_bounds__(512, 2) void lstm8(
    const float* __restrict__ x,            // [B][1][H][W]
    const short* __restrict__ Bp,           // [3][512][128]
    const float* __restrict__ pxw,          // [3][512]
    const float* __restrict__ pb,           // [512]
    const __hip_bfloat16* __restrict__ hIn, // [B][W][CH] = h(t0-1)
    __hip_bfloat16* __restrict__ hOut,      // [B][W][CH] = h(t0+7)
    const float* __restrict__ cIn,          // [B][W][CH]
    float* __restrict__ cOut,               // [B][W][CH]
    float* __restrict__ pooled,             // [B][CH]
    int t0)
{
    __shared__ alignas(16) short SA[ROWS * 128];  // swizzled h slab (ping)
    __shared__ alignas(16) short SB[ROWS * 128];  // swizzled h slab (pong)
    __shared__ float xs[kT][ROWS];

    const int tid  = threadIdx.x;
    const int lane = tid & 63;
    const int wave = tid >> 6;
    const int w0   = blockIdx.x * 128;
    const int b    = blockIdx.y;

    const int ncol = lane & 15;
    const int krow = lane >> 4;
    const int ch   = wave * 16 + ncol;  // 0..127

    // per-lane constants: bias + x-channel conv weights
    float wxk[4][3], bia[4];
#pragma unroll
    for (int g = 0; g < 4; ++g) {
        bia[g] = pb[g * 128 + ch];
#pragma unroll
        for (int kx = 0; kx < 3; ++kx)
            wxk[g][kx] = pxw[kx * 512 + g * 128 + ch];
    }

    const float* xb = x + ((size_t)b * kH + t0) * kW;
    const size_t gbase = (size_t)b * kW * kCH;

    // ---- staging: h(t0-1) slab (rows w0-9 .. w0+136) + 8 x rows ----
    if (!FIRST) {
        for (int i = tid; i < ROWS * 16; i += 512) {
            int row = i >> 4, col = i & 15;
            int w = w0 - 9 + row;
            short8v v = {0, 0, 0, 0, 0, 0, 0, 0};
            if (w >= 0 && w < kW)
                v = *reinterpret_cast<const short8v*>(
                    reinterpret_cast<const short*>(hIn) +
                    (gbase + (size_t)w * kCH + col * 8));
            *reinterpret_cast<short8v*>(
                SA + row * 128 + (col ^ (row & 7)) * 8) = v;
        }
    }
#pragma unroll
    for (int s8 = 0; s8 < kT; ++s8) {
        for (int j = tid; j < ROWS; j += 512) {
            int w = w0 - 9 + j;
            xs[s8][j] = (w >= 0 && w < kW) ? xb[s8 * kW + w] : 0.0f;
        }
    }
    __syncthreads();

    float creg[9][4];
#pragma unroll
    for (int mf = 0; mf < 9; ++mf)
#pragma unroll
        for (int r = 0; r < 4; ++r) creg[mf][r] = 0.0f;
    float psum = 0.0f;

    for (int s = 0; s < kT; ++s) {
        const short* Sr = (s & 1) ? SB : SA;
        short* Sw       = (s & 1) ? SA : SB;

        float4v acc[9][4];  // [mfrag][gate]
#pragma unroll
        for (int mf = 0; mf < 9; ++mf)
#pragma unroll
            for (int g = 0; g < 4; ++g)
                acc[mf][g] = float4v{0.f, 0.f, 0.f, 0.f};

        if (!(FIRST && s == 0)) {
#pragma unroll
            for (int kx = 0; kx < 3; ++kx) {
#pragma unroll
                for (int ks = 0; ks < 4; ++ks) {
                    short8v bfr[4];
#pragma unroll
                    for (int g = 0; g < 4; ++g)
                        bfr[g] = *reinterpret_cast<const short8v*>(
                            Bp + ((kx * 512 + g * 128 + ch) * 128 +
                                  ks * 32 + krow * 8));
#pragma unroll
                    for (int mf = 0; mf < 9; ++mf) {
                        int srow = mf * 16 + ncol + kx;
                        int slot = (ks * 4 + krow) ^ (srow & 7);
                        short8v afr = *reinterpret_cast<const short8v*>(
                            Sr + srow * 128 + slot * 8);
#pragma unroll
                        for (int g = 0; g < 4; ++g)
                            acc[mf][g] = __builtin_amdgcn_mfma_f32_16x16x32_bf16(
                                afr, bfr[g], acc[mf][g], 0, 0, 0);
                    }
                }
            }
        }

        // epilogue: gates + state update, h -> other slab (or global/pool)
#pragma unroll
        for (int mf = 0; mf < 9; ++mf) {
#pragma unroll
            for (int r = 0; r < 4; ++r) {
                int m = mf * 16 + krow * 4 + r;
                int w = w0 - 8 + m;
                bool inimg = (w >= 0) && (w < kW);
                bool valid = (m >= s + 1) && (m <= 142 - s) && inimg;
                float xm = xs[s][m], xc = xs[s][m + 1], xp = xs[s][m + 2];
                float v0 = acc[mf][0][r] + bia[0] + xm * wxk[0][0] + xc * wxk[0][1] + xp * wxk[0][2];
                float v1 = acc[mf][1][r] + bia[1] + xm * wxk[1][0] + xc * wxk[1][1] + xp * wxk[1][2];
                float v2 = acc[mf][2][r] + bia[2] + xm * wxk[2][0] + xc * wxk[2][1] + xp * wxk[2][2];
                float v3 = acc[mf][3][r] + bia[3] + xm * wxk[3][0] + xc * wxk[3][1] + xp * wxk[3][2];
                float cprev;
                if (s == 0) {
                    cprev = (FIRST || !inimg) ? 0.0f
                          : cIn[gbase + (size_t)w * kCH + ch];
                } else {
                    cprev = creg[mf][r];
                }
                float si = fsig(v0), sf = fsig(v1);
                float tg = ftanh(v2), so = fsig(v3);
                float cn = sf * cprev + si * tg;
                float hn = so * ftanh(cn);
                creg[mf][r] = cn;
                if (s < kT - 1) {
                    __hip_bfloat16 hv = __float2bfloat16(valid ? hn : 0.0f);
                    int j2 = m + 1;  // slab row for w
                    Sw[j2 * 128 + ((ch >> 3) ^ (j2 & 7)) * 8 + (ch & 7)] =
                        *reinterpret_cast<short*>(&hv);
                } else if (LAST) {
                    if (valid) psum += hn;
                } else if (m >= 8 && m < 136) {
                    size_t gi = gbase + (size_t)w * kCH + ch;
                    hOut[gi] = __float2bfloat16(hn);
                    cOut[gi] = cn;
                }
            }
        }
        __syncthreads();
    }

    if (LAST) {
        psum += __shfl_xor(psum, 16, 64);
        psum += __shfl_xor(psum, 32, 64);
        if (krow == 0) atomicAdd(&pooled[b * kCH + ch], psum);
    }
}

// ---------------------------------------------------------------------------
// Final FC from pooled sums. grid = B, block = 64.
// ---------------------------------------------------------------------------
__global__ __launch_bounds__(64) void fc_final(
    const float* __restrict__ pooled,  // [B][CH] raw sums over W
    const float* __restrict__ fc_w,    // [NC][CH]
    const float* __restrict__ fc_b,    // [NC]
    float* __restrict__ out)           // [B][NC]
{
    int b = blockIdx.x, nc = threadIdx.x;
    if (nc < kNC) {
        float s = 0.0f;
        for (int k = 0; k < kCH; ++k)
            s = fmaf(pooled[b * kCH + k], fc_w[nc * kCH + k], s);
        out[b * kNC + nc] = fc_b[nc] + s * (1.0f / kW);
    }
}

// ---------------------------------------------------------------------------
extern "C" void kernel_launch(void* const* d_in, const int* in_sizes, int n_in,
                              void* d_out, int out_size, void* d_ws, size_t ws_size,
                              hipStream_t stream) {
    const float* x      = (const float*)d_in[0];
    const float* conv_w = (const float*)d_in[1];
    const float* conv_b = (const float*)d_in[2];
    const float* fc_w   = (const float*)d_in[3];
    const float* fc_b   = (const float*)d_in[4];
    float* out = (float*)d_out;

    const size_t stateN = (size_t)kB * kW * kCH;  // 4,194,304
    float* cA           = (float*)d_ws;
    float* cB           = cA + stateN;
    __hip_bfloat16* hA  = (__hip_bfloat16*)(cB + stateN);
    __hip_bfloat16* hB  = hA + stateN;
    short* Bp           = (short*)(hB + stateN);
    float* pxw          = (float*)(Bp + 3 * 512 * 128);
    float* pb           = pxw + 3 * 512;
    float* pooled       = pb + 512;  // [64][128]

    pack_weights<<<768, 256, 0, stream>>>(conv_w, conv_b, Bp, pxw, pb, pooled);

    dim3 grid(kW / 128, kB);
    dim3 block(512);
    // launch k handles t = 8k..8k+7. write(k) = k even ? (hB,cB) : (hA,cA);
    // read(k) = write(k-1).
    lstm8<true, false><<<grid, block, 0, stream>>>(
        x, Bp, pxw, pb, hA, hB, cA, cB, pooled, 0);
    for (int k = 1; k < 15; ++k) {
        __hip_bfloat16* hi = (k & 1) ? hB : hA;
        __hip_bfloat16* ho = (k & 1) ? hA : hB;
        float* ci = (k & 1) ? cB : cA;
        float* co = (k & 1) ? cA : cB;
        lstm8<false, false><<<grid, block, 0, stream>>>(
            x, Bp, pxw, pb, hi, ho, ci, co, pooled, 8 * k);
    }
    // k = 15 (odd): reads (hB,cB); outputs pooled only.
    lstm8<false, true><<<grid, block, 0, stream>>>(
        x, Bp, pxw, pb, hB, hA, cB, cA, pooled, 120);

    fc_final<<<kB, 64, 0, stream>>>(pooled, fc_w, fc_b, out);
}